// Round 6
// baseline (139.127 us; speedup 1.0000x reference)
//
#include <hip/hip_runtime.h>
#include <hip/hip_bf16.h>
#include <cstdint>

// Problem constants
#define BATCH 8192
#define IN_F  1024
#define OUT_F 1024
#define G_HRS 1e-6f
#define G_LRS 1e-3f
#define PAR_R 2.0f
#define LEVELS 15.0f   // 2^4 - 1

// workspace layout (bytes)
#define WS_PMIN  0                        // 256 f32 per-block min partials
#define WS_PMAX  1024                     // 256 f32 per-block max partials
#define WS_VEFF  4096                     // 1024 f32
#define WS_VID   8192                     // 1024 f32
#define WS_CORR  16384                    // 32 KB (8192 f32)
#define WS_BT    65536                    // 2 MB bf16 W_effT
#define WS_ABF   (65536 + 2097152)        // 16 MB bf16 x
#define WS_NEED_FULL  ((size_t)WS_ABF + (size_t)BATCH * IN_F * 2)

// ---------- helpers ----------
__device__ __forceinline__ unsigned short f2bf(float f) {
    union { float f; unsigned int i; } v; v.f = f;
    unsigned int u = v.i;
    unsigned int r = (u + 0x7FFFu + ((u >> 16) & 1u)) >> 16;  // RNE
    return (unsigned short)r;
}
__device__ __forceinline__ float quant_g(float wv, float wmin, float inv_range) {
    float t = (wv - wmin) * inv_range;                    // [0,1]
    float step = (G_LRS - G_HRS) / LEVELS;
    return rintf(t * LEVELS) * step + G_HRS;              // rintf = RNE = jnp.round
}

// ---------- K1: per-block min/max partials over weight; block 0 zeros veff/vid ----------
// NOTE (R3 post-mortem): do NOT fuse K1-K3 via hipLaunchCooperativeKernel. grid.sync()
// on 8-XCD MI355X costs ~50us per sync (cross-XCD L2 coherence); plain same-stream
// launch-to-launch latency (~2us) is the cheap sync primitive here.
__global__ void kprep(const float* __restrict__ w, float* __restrict__ pmin, float* __restrict__ pmax,
                      float* __restrict__ veff, float* __restrict__ vid) {
    int tid = blockIdx.x * blockDim.x + threadIdx.x;
    float lo = 1e30f, hi = -1e30f;
    const float4* w4 = (const float4*)w;
    const int n4 = (IN_F * OUT_F) / 4;                    // 262144
    for (int i = tid; i < n4; i += 256 * 256) {
        float4 q = w4[i];
        lo = fminf(lo, fminf(fminf(q.x, q.y), fminf(q.z, q.w)));
        hi = fmaxf(hi, fmaxf(fmaxf(q.x, q.y), fmaxf(q.z, q.w)));
    }
#pragma unroll
    for (int m = 1; m < 64; m <<= 1) {
        lo = fminf(lo, __shfl_xor(lo, m, 64));
        hi = fmaxf(hi, __shfl_xor(hi, m, 64));
    }
    __shared__ float slo[4], shi[4];
    int wv = threadIdx.x >> 6, ln = threadIdx.x & 63;
    if (ln == 0) { slo[wv] = lo; shi[wv] = hi; }
    __syncthreads();
    if (threadIdx.x == 0) {
        pmin[blockIdx.x] = fminf(fminf(slo[0], slo[1]), fminf(slo[2], slo[3]));
        pmax[blockIdx.x] = fmaxf(fmaxf(shi[0], shi[1]), fmaxf(shi[2], shi[3]));
    }
    if (blockIdx.x == 0) {                                 // zero accumulators for K2's atomics
        float4 z = make_float4(0.f, 0.f, 0.f, 0.f);
        ((float4*)veff)[threadIdx.x] = z;                  // 256 * 4 = 1024
        ((float4*)vid)[threadIdx.x]  = z;
    }
}

// ---------- K2: build W_effT bf16 + accumulate veff/vid ----------
// R5 post-mortem: the 64-block variant showed 2.4% occupancy, 1.9% VALU, 24 VGPR --
// latency-starved on the double-divide chains. Back to 256 blocks x 4 rows (R0-proven
// atomic load: 256 adds/address) and load-all-then-compute so the 16 independent
// divide chains overlap (raises VGPR/ILP instead of serializing on 24 regs).
__global__ void kbuildvec(const float* __restrict__ w, const float* __restrict__ pmin,
                          const float* __restrict__ pmax, unsigned short* __restrict__ bt,
                          float* __restrict__ veff, float* __restrict__ vid) {
    float lo = pmin[threadIdx.x], hi = pmax[threadIdx.x];
#pragma unroll
    for (int m = 1; m < 64; m <<= 1) {
        lo = fminf(lo, __shfl_xor(lo, m, 64));
        hi = fmaxf(hi, __shfl_xor(hi, m, 64));
    }
    __shared__ float slo[4], shi[4];
    int wv = threadIdx.x >> 6, ln = threadIdx.x & 63;
    if (ln == 0) { slo[wv] = lo; shi[wv] = hi; }
    __syncthreads();
    float wmin = fminf(fminf(slo[0], slo[1]), fminf(slo[2], slo[3]));
    float wmax = fmaxf(fmaxf(shi[0], shi[1]), fmaxf(shi[2], shi[3]));

    float inv_range = 1.0f / (wmax - wmin);
    float acoef = (G_LRS - G_HRS) * inv_range;
    float bcoef = G_HRS - acoef * wmin;
    float inva = 1.0f / acoef;

    int k0 = threadIdx.x * 4;

    // load all 4 row-fragments first (16 independent elements in registers)
    float4 q[4];
#pragma unroll
    for (int rr = 0; rr < 4; rr++) {
        int n = blockIdx.x * 4 + rr;
        q[rr] = *(const float4*)&w[(size_t)n * IN_F + k0];
    }

    float se[4] = {0.f, 0.f, 0.f, 0.f}, si[4] = {0.f, 0.f, 0.f, 0.f};
#pragma unroll
    for (int rr = 0; rr < 4; rr++) {
        int n = blockIdx.x * 4 + rr;
        float wvv[4] = { q[rr].x, q[rr].y, q[rr].z, q[rr].w };
        unsigned short o[4];
#pragma unroll
        for (int j = 0; j < 4; j++) {
            int k = k0 + j;
            float g = quant_g(wvv[j], wmin, inv_range);
            float r = PAR_R * ((float)(n + 1) + (float)(IN_F - k));
            float ge = 1.0f / (1.0f / g + r);
            o[j] = f2bf((ge - bcoef) * inva);
            se[j] += ge;
            si[j] += g;
        }
        uint2 ov;
        ov.x = (unsigned int)o[0] | ((unsigned int)o[1] << 16);
        ov.y = (unsigned int)o[2] | ((unsigned int)o[3] << 16);
        *(uint2*)&bt[(size_t)n * IN_F + k0] = ov;
    }
#pragma unroll
    for (int j = 0; j < 4; j++) {
        atomicAdd(&veff[k0 + j], se[j]);
        atomicAdd(&vid[k0 + j], si[j]);
    }
}

// ---------- K3: corr[row] = (x.v_eff)/(x.v_id); emit bf16 copy of x ----------
// barrier-free: one wave per row, 4 rows per block. Fully-coalesced pattern:
// iteration p, lane l touches floats [p*256 + l*4, +4) -> 1KB contiguous per wave inst.
__global__ void kcorr(const float* __restrict__ x, const float* __restrict__ veff,
                      const float* __restrict__ vid, float* __restrict__ corr,
                      unsigned short* __restrict__ abf) {
    int row = blockIdx.x * 4 + (threadIdx.x >> 6);
    int lane = threadIdx.x & 63;
    const float* xr = x + (size_t)row * IN_F;
    float se = 0.f, si = 0.f;
#pragma unroll
    for (int p = 0; p < 4; p++) {
        int off = p * 256 + lane * 4;
        float4 q  = *(const float4*)(xr + off);
        float4 ve = *(const float4*)(veff + off);
        float4 vi = *(const float4*)(vid  + off);
        se += q.x * ve.x + q.y * ve.y + q.z * ve.z + q.w * ve.w;
        si += q.x * vi.x + q.y * vi.y + q.z * vi.z + q.w * vi.w;
        if (abf) {
            uint2 ov;
            ov.x = (unsigned int)f2bf(q.x) | ((unsigned int)f2bf(q.y) << 16);
            ov.y = (unsigned int)f2bf(q.z) | ((unsigned int)f2bf(q.w) << 16);
            *(uint2*)&abf[(size_t)row * IN_F + off] = ov;
        }
    }
#pragma unroll
    for (int m = 1; m < 64; m <<= 1) {
        se += __shfl_xor(se, m, 64);
        si += __shfl_xor(si, m, 64);
    }
    if (lane == 0) corr[row] = se / si;
}

// ---------- K4 common ----------
typedef __attribute__((ext_vector_type(8))) short bf16x8;
typedef __attribute__((ext_vector_type(4))) float f32x4;

#define GLD_LDS16(g, l) \
    __builtin_amdgcn_global_load_lds((const __attribute__((address_space(1))) void*)(g), \
                                     (__attribute__((address_space(3))) void*)(l), 16, 0, 0)

#define SCHED0   __builtin_amdgcn_sched_barrier(0)
#define LGKM(n)  do { asm volatile("s_waitcnt lgkmcnt(" #n ")" ::: "memory"); SCHED0; } while (0)
#define VMCNT(n) asm volatile("s_waitcnt vmcnt(" #n ")" ::: "memory")
#define SBAR     asm volatile("s_barrier" ::: "memory")

#define MFMA_ROW4(MT, A, B0, B1, B2, B3) \
    acc[MT][0] = __builtin_amdgcn_mfma_f32_16x16x32_bf16(A, B0, acc[MT][0], 0, 0, 0); \
    acc[MT][1] = __builtin_amdgcn_mfma_f32_16x16x32_bf16(A, B1, acc[MT][1], 0, 0, 0); \
    acc[MT][2] = __builtin_amdgcn_mfma_f32_16x16x32_bf16(A, B2, acc[MT][2], 0, 0, 0); \
    acc[MT][3] = __builtin_amdgcn_mfma_f32_16x16x32_bf16(A, B3, acc[MT][3], 0, 0, 0);

// ---------- K4 (full path): pipelined GEMM, 128x128 tile, BK=64, 4 waves.
// Schedule (correctness-verified in R3/R5 runs): all 8 next-tile stages issue in ph0
// (B'x4) / ph1 (A'u0,u2 then u1,u3; order pinned). S1 = vmcnt(4) retires prev A'u1,u3
// (3 phases old); S2 = vmcnt(2) retires B'x4 + A'u0,u2, leaves A'u1,u3 in flight.
// WAR-safe: all ds_reads of a buffer complete before its overwrite barrier.
__global__ __launch_bounds__(256) void kgemm2(
    const unsigned short* __restrict__ Abf,  // x bf16 [8192,1024]
    const unsigned short* __restrict__ Bt,   // W_effT [1024,1024] bf16
    const float* __restrict__ bias,          // [1024] f32
    const float* __restrict__ corr,          // [8192] f32
    float* __restrict__ out)                 // [8192,1024] f32
{
    __shared__ unsigned short As[2 * 128 * 64];   // 2 x 16KB
    __shared__ unsigned short Bs[2 * 128 * 64];   // 2 x 16KB
    const int tid = threadIdx.x;
    const int f = blockIdx.x;
    const int bm = ((f & 7) * 8 + ((f >> 3) & 7)) * 128;
    const int bn = (f >> 6) * 128;
    const int wave = tid >> 6, lane = tid & 63;
    const int wmL = (wave >> 1) * 64;
    const int wnL = (wave & 1) * 64;
    const int fr = lane & 15;
    const int quad = lane >> 4;

    const int sw   = (fr & 7) * 16;
    const int aRd0 = (wmL + fr) * 128 + ((quad * 16) ^ sw);        // ks=0
    const int aRd1 = (wmL + fr) * 128 + (((64 + quad * 16)) ^ sw); // ks=1
    const int bRd0 = (wnL + fr) * 128 + ((quad * 16) ^ sw);
    const int bRd1 = (wnL + fr) * 128 + (((64 + quad * 16)) ^ sw);

    const int arow  = tid >> 3;                                  // 0..31
    const int acolb = ((tid & 7) * 16) ^ ((arow & 7) * 16);
    const unsigned short* gA = Abf + (size_t)(bm + arow) * IN_F + (acolb >> 1);
    const unsigned short* gB = Bt  + (size_t)(bn + arow) * IN_F + (acolb >> 1);

    f32x4 acc[4][4] = {};

    // ---- prologue: stage tile 0 into buf0, drain once, publish
    {
        unsigned short* lA = As + tid * 8;
        unsigned short* lB = Bs + tid * 8;
        GLD_LDS16(gB,              lB);
        GLD_LDS16(gB + 32 * IN_F,  lB + 2048);
        GLD_LDS16(gB + 64 * IN_F,  lB + 4096);
        GLD_LDS16(gB + 96 * IN_F,  lB + 6144);
        GLD_LDS16(gA,              lA);
        GLD_LDS16(gA + 32 * IN_F,  lA + 2048);
        GLD_LDS16(gA + 64 * IN_F,  lA + 4096);
        GLD_LDS16(gA + 96 * IN_F,  lA + 6144);
        VMCNT(0);
        SBAR;
    }

#pragma unroll 1
    for (int t = 0; t < 15; ++t) {
        const int rb = (t & 1) << 13;          // read buf ushort offset (0 / 8192)
        const int wb = rb ^ 8192;
        const int kbn = t * 64 + 64;
        const char* Ar = (const char*)(As + rb);
        const char* Br = (const char*)(Bs + rb);
        unsigned short* Aw = As + wb + tid * 8;
        unsigned short* Bw = Bs + wb + tid * 8;
        bf16x8 b0, b1, b2, b3, a0, a1;     // ks0 frags
        bf16x8 c0, c1, c2, c3, p0, p1;     // ks1 prefetch (B all, A mt0/mt1)
        bf16x8 q0, q1;                     // ks1 A mt2/mt3 prefetch

        // ---- phase 0: ks0 x mt{0,1}; prefetch ph2 reads; stage B'u0-u3
        b0 = *(const bf16x8*)(Br + bRd0);
        b1 = *(const bf16x8*)(Br + bRd0 + 2048);
        b2 = *(const bf16x8*)(Br + bRd0 + 4096);
        b3 = *(const bf16x8*)(Br + bRd0 + 6144);
        a0 = *(const bf16x8*)(Ar + aRd0);
        a1 = *(const bf16x8*)(Ar + aRd0 + 2048);
        SCHED0;                                    // pin group order for counted lgkm
        c0 = *(const bf16x8*)(Br + bRd1);
        c1 = *(const bf16x8*)(Br + bRd1 + 2048);
        c2 = *(const bf16x8*)(Br + bRd1 + 4096);
        c3 = *(const bf16x8*)(Br + bRd1 + 6144);
        p0 = *(const bf16x8*)(Ar + aRd1);
        p1 = *(const bf16x8*)(Ar + aRd1 + 2048);
        GLD_LDS16(gB + kbn,             Bw);
        GLD_LDS16(gB + 32 * IN_F + kbn, Bw + 2048);
        GLD_LDS16(gB + 64 * IN_F + kbn, Bw + 4096);
        GLD_LDS16(gB + 96 * IN_F + kbn, Bw + 6144);
        LGKM(6);                                   // own 6 done; prefetch 6 may pend
        __builtin_amdgcn_s_setprio(1);
        MFMA_ROW4(0, a0, b0, b1, b2, b3)
        MFMA_ROW4(1, a1, b0, b1, b2, b3)
        __builtin_amdgcn_s_setprio(0);
        SCHED0;
        VMCNT(4);                                  // retires prev tile's A'u1,u3
        SBAR;

        // ---- phase 1: ks0 x mt{2,3}; prefetch ph3's A; stage A'u0,u2 then u1,u3
        a0 = *(const bf16x8*)(Ar + aRd0 + 4096);
        a1 = *(const bf16x8*)(Ar + aRd0 + 6144);
        SCHED0;
        q0 = *(const bf16x8*)(Ar + aRd1 + 4096);
        q1 = *(const bf16x8*)(Ar + aRd1 + 6144);
        GLD_LDS16(gA + kbn,             Aw);
        GLD_LDS16(gA + 64 * IN_F + kbn, Aw + 4096);
        SCHED0;                                    // pin A' issue order: u0,u2 before u1,u3
        GLD_LDS16(gA + 32 * IN_F + kbn, Aw + 2048);
        GLD_LDS16(gA + 96 * IN_F + kbn, Aw + 6144);
        LGKM(2);                                   // own 2 + ph0 prefetch done; q0/q1 pend
        __builtin_amdgcn_s_setprio(1);
        MFMA_ROW4(2, a0, b0, b1, b2, b3)
        MFMA_ROW4(3, a1, b0, b1, b2, b3)
        __builtin_amdgcn_s_setprio(0);
        SCHED0;

        // ---- phase 2: ks1 x mt{0,1} — data already in c*/p* registers
        LGKM(2);                                   // no-op belt+suspenders
        __builtin_amdgcn_s_setprio(1);
        MFMA_ROW4(0, p0, c0, c1, c2, c3)
        MFMA_ROW4(1, p1, c0, c1, c2, c3)
        __builtin_amdgcn_s_setprio(0);
        SCHED0;

        // ---- phase 3: ks1 x mt{2,3} — q0/q1 landed under ph2's MFMAs
        LGKM(0);
        __builtin_amdgcn_s_setprio(1);
        MFMA_ROW4(2, q0, c0, c1, c2, c3)
        MFMA_ROW4(3, q1, c0, c1, c2, c3)
        __builtin_amdgcn_s_setprio(0);
        SCHED0;
        VMCNT(2);                                  // retires B'x4 + A'u0,u2
        SBAR;
    }

    // ---- peeled tile 15 (buf1): no stages; first vmcnt drains last 2 in-flight loads.
    {
        const char* Ar = (const char*)(As + 8192);
        const char* Br = (const char*)(Bs + 8192);
        bf16x8 b0, b1, b2, b3, a0, a1;

        b0 = *(const bf16x8*)(Br + bRd0);
        b1 = *(const bf16x8*)(Br + bRd0 + 2048);
        b2 = *(const bf16x8*)(Br + bRd0 + 4096);
        b3 = *(const bf16x8*)(Br + bRd0 + 6144);
        a0 = *(const bf16x8*)(Ar + aRd0);
        a1 = *(const bf16x8*)(Ar + aRd0 + 2048);
        LGKM(0);
        __builtin_amdgcn_s_setprio(1);
        MFMA_ROW4(0, a0, b0, b1, b2, b3)
        MFMA_ROW4(1, a1, b0, b1, b2, b3)
        __builtin_amdgcn_s_setprio(0);
        SCHED0;
        VMCNT(0);
        SBAR;

        a0 = *(const bf16x8*)(Ar + aRd0 + 4096);
        a1 = *(const bf16x8*)(Ar + aRd0 + 6144);
        LGKM(0);
        __builtin_amdgcn_s_setprio(1);
        MFMA_ROW4(2, a0, b0, b1, b2, b3)
        MFMA_ROW4(3, a1, b0, b1, b2, b3)
        __builtin_amdgcn_s_setprio(0);
        SCHED0;

        b0 = *(const bf16x8*)(Br + bRd1);
        b1 = *(const bf16x8*)(Br + bRd1 + 2048);
        b2 = *(const bf16x8*)(Br + bRd1 + 4096);
        b3 = *(const bf16x8*)(Br + bRd1 + 6144);
        a0 = *(const bf16x8*)(Ar + aRd1);
        a1 = *(const bf16x8*)(Ar + aRd1 + 2048);
        LGKM(0);
        __builtin_amdgcn_s_setprio(1);
        MFMA_ROW4(0, a0, b0, b1, b2, b3)
        MFMA_ROW4(1, a1, b0, b1, b2, b3)
        __builtin_amdgcn_s_setprio(0);
        SCHED0;

        a0 = *(const bf16x8*)(Ar + aRd1 + 4096);
        a1 = *(const bf16x8*)(Ar + aRd1 + 6144);
        LGKM(0);
        __builtin_amdgcn_s_setprio(1);
        MFMA_ROW4(2, a0, b0, b1, b2, b3)
        MFMA_ROW4(3, a1, b0, b1, b2, b3)
        __builtin_amdgcn_s_setprio(0);
        SCHED0;
    }

    // epilogue: out[r][c] = acc + bias[c]*corr[r]  (C/D: col=lane&15, row=quad*4+reg)
#pragma unroll
    for (int nt = 0; nt < 4; nt++) {
        int gc = bn + wnL + nt * 16 + fr;
        float bv = bias[gc];
#pragma unroll
        for (int mt = 0; mt < 4; mt++) {
#pragma unroll
            for (int r = 0; r < 4; r++) {
                int gr = bm + wmL + mt * 16 + quad * 4 + r;
                out[(size_t)gr * OUT_F + gc] = acc[mt][nt][r] + bv * corr[gr];
            }
        }
    }
}

// ---------- K4 fallback (small workspace): converts x f32 -> bf16 in-kernel ----------
__global__ __launch_bounds__(256) void kgemm_conva(
    const float* __restrict__ Af32,
    const unsigned short* __restrict__ Bt,   // W_effT [1024,1024] bf16
    const float* __restrict__ bias,          // [1024] f32
    const float* __restrict__ corr,          // [8192] f32
    float* __restrict__ out)                 // [8192,1024] f32
{
    __shared__ unsigned short As0[128 * 32];
    __shared__ unsigned short As1[128 * 32];
    __shared__ unsigned short Bs0[128 * 32];
    __shared__ unsigned short Bs1[128 * 32];
    const int tid = threadIdx.x;
    const int f = blockIdx.x;
    const int bm = ((f & 7) * 8 + ((f >> 3) & 7)) * 128;
    const int bn = (f >> 6) * 128;
    const int wave = tid >> 6, lane = tid & 63;
    const int wmL = (wave >> 1) * 64;
    const int wnL = (wave & 1) * 64;
    const int fr = lane & 15;
    const int fk = (lane >> 4) * 8;
    const int quad = lane >> 4;

    f32x4 acc[4][4] = {};

    const int c0 = tid, c1 = tid + 256;
    const unsigned short* gB0 = Bt + (size_t)(bn + (c0 >> 2)) * IN_F + ((c0 & 3) << 3);
    const unsigned short* gB1 = Bt + (size_t)(bn + (c1 >> 2)) * IN_F + ((c1 & 3) << 3);
    const float* fA0 = Af32 + (size_t)(bm + (c0 >> 2)) * IN_F + ((c0 & 3) << 3);
    const float* fA1 = Af32 + (size_t)(bm + (c1 >> 2)) * IN_F + ((c1 & 3) << 3);

    for (int kb = 0; kb < IN_F; kb += 64) {
        float4 p[8];
        p[0] = *(const float4*)(fA0 + kb);      p[1] = *(const float4*)(fA0 + kb + 4);
        p[2] = *(const float4*)(fA1 + kb);      p[3] = *(const float4*)(fA1 + kb + 4);
        p[4] = *(const float4*)(fA0 + kb + 32); p[5] = *(const float4*)(fA0 + kb + 36);
        p[6] = *(const float4*)(fA1 + kb + 32); p[7] = *(const float4*)(fA1 + kb + 36);
        uint4 u[4];
#pragma unroll
        for (int j = 0; j < 4; j++) {
            u[j] = make_uint4(
                (unsigned int)f2bf(p[2*j].x) | ((unsigned int)f2bf(p[2*j].y) << 16),
                (unsigned int)f2bf(p[2*j].z) | ((unsigned int)f2bf(p[2*j].w) << 16),
                (unsigned int)f2bf(p[2*j+1].x) | ((unsigned int)f2bf(p[2*j+1].y) << 16),
                (unsigned int)f2bf(p[2*j+1].z) | ((unsigned int)f2bf(p[2*j+1].w) << 16));
        }
        __syncthreads();
        *(uint4*)&As0[c0 * 8] = u[0];
        *(uint4*)&As0[c1 * 8] = u[1];
        *(uint4*)&As1[c0 * 8] = u[2];
        *(uint4*)&As1[c1 * 8] = u[3];
        GLD_LDS16(gB0 + kb, &Bs0[c0 * 8]);
        GLD_LDS16(gB1 + kb, &Bs0[c1 * 8]);
        GLD_LDS16(gB0 + kb + 32, &Bs1[c0 * 8]);
        GLD_LDS16(gB1 + kb + 32, &Bs1[c1 * 8]);
        __syncthreads();

        bf16x8 af[4], bfv[4];
#pragma unroll
        for (int mt = 0; mt < 4; mt++)
            af[mt] = *(const bf16x8*)&As0[(wmL + mt * 16 + fr) * 32 + fk];
#pragma unroll
        for (int nt = 0; nt < 4; nt++)
            bfv[nt] = *(const bf16x8*)&Bs0[(wnL + nt * 16 + fr) * 32 + fk];
#pragma unroll
        for (int mt = 0; mt < 4; mt++)
#pragma unroll
            for (int nt = 0; nt < 4; nt++)
                acc[mt][nt] = __builtin_amdgcn_mfma_f32_16x16x32_bf16(af[mt], bfv[nt], acc[mt][nt], 0, 0, 0);
#pragma unroll
        for (int mt = 0; mt < 4; mt++)
            af[mt] = *(const bf16x8*)&As1[(wmL + mt * 16 + fr) * 32 + fk];
#pragma unroll
        for (int nt = 0; nt < 4; nt++)
            bfv[nt] = *(const bf16x8*)&Bs1[(wnL + nt * 16 + fr) * 32 + fk];
#pragma unroll
        for (int mt = 0; mt < 4; mt++)
#pragma unroll
            for (int nt = 0; nt < 4; nt++)
                acc[mt][nt] = __builtin_amdgcn_mfma_f32_16x16x32_bf16(af[mt], bfv[nt], acc[mt][nt], 0, 0, 0);
    }

#pragma unroll
    for (int nt = 0; nt < 4; nt++) {
        int gc = bn + wnL + nt * 16 + fr;
        float bv = bias[gc];
#pragma unroll
        for (int mt = 0; mt < 4; mt++) {
#pragma unroll
            for (int r = 0; r < 4; r++) {
                int gr = bm + wmL + mt * 16 + quad * 4 + r;
                out[(size_t)gr * OUT_F + gc] = acc[mt][nt][r] + bv * corr[gr];
            }
        }
    }
}

// ---------- launch ----------
extern "C" void kernel_launch(void* const* d_in, const int* in_sizes, int n_in,
                              void* d_out, int out_size, void* d_ws, size_t ws_size,
                              hipStream_t stream) {
    const float* x    = (const float*)d_in[0];   // [8192,1024] f32
    const float* w    = (const float*)d_in[1];   // [1024,1024] f32 (out,in)
    const float* bias = (const float*)d_in[2];   // [1024] f32
    float* out = (float*)d_out;

    char* ws = (char*)d_ws;
    float* pmin        = (float*)(ws + WS_PMIN);
    float* pmax        = (float*)(ws + WS_PMAX);
    float* veff        = (float*)(ws + WS_VEFF);
    float* vid         = (float*)(ws + WS_VID);
    float* corr        = (float*)(ws + WS_CORR);
    unsigned short* bt = (unsigned short*)(ws + WS_BT);
    unsigned short* abf = (unsigned short*)(ws + WS_ABF);

    bool full = ws_size >= WS_NEED_FULL;

    kprep<<<256, 256, 0, stream>>>(w, pmin, pmax, veff, vid);
    kbuildvec<<<OUT_F / 4, 256, 0, stream>>>(w, pmin, pmax, bt, veff, vid);
    kcorr<<<BATCH / 4, 256, 0, stream>>>(x, veff, vid, corr, full ? abf : nullptr);
    if (full)
        kgemm2<<<512, 256, 0, stream>>>(abf, bt, bias, corr, out);
    else
        kgemm_conva<<<512, 256, 0, stream>>>(x, bt, bias, corr, out);
}

// Round 7
// 125.347 us; speedup vs baseline: 1.1099x; 1.1099x over previous
//
#include <hip/hip_runtime.h>
#include <hip/hip_bf16.h>
#include <cstdint>

// Problem constants
#define BATCH 8192
#define IN_F  1024
#define OUT_F 1024
#define G_HRS 1e-6f
#define G_LRS 1e-3f
#define PAR_R 2.0f
#define LEVELS 15.0f   // 2^4 - 1

// workspace layout (bytes)
#define WS_PMIN  0                        // 256 f32 per-block min partials
#define WS_PMAX  1024                     // 256 f32 per-block max partials
#define WS_VEFF  4096                     // 1024 f32
#define WS_VID   8192                     // 1024 f32
#define WS_CORR  16384                    // 32 KB (8192 f32)
#define WS_BT    65536                    // 2 MB bf16 W_effT
#define WS_ABF   (65536 + 2097152)        // 16 MB bf16 x
#define WS_NEED_FULL  ((size_t)WS_ABF + (size_t)BATCH * IN_F * 2)

// ---------- helpers ----------
__device__ __forceinline__ unsigned short f2bf(float f) {
    union { float f; unsigned int i; } v; v.f = f;
    unsigned int u = v.i;
    unsigned int r = (u + 0x7FFFu + ((u >> 16) & 1u)) >> 16;  // RNE
    return (unsigned short)r;
}
__device__ __forceinline__ float quant_g(float wv, float wmin, float inv_range) {
    float t = (wv - wmin) * inv_range;                    // [0,1]
    float step = (G_LRS - G_HRS) / LEVELS;
    return rintf(t * LEVELS) * step + G_HRS;              // rintf = RNE = jnp.round
}

// ---------- K1: per-block min/max partials over weight; block 0 zeros veff/vid ----------
// NOTE (R3 post-mortem): do NOT fuse K1-K3 via hipLaunchCooperativeKernel. grid.sync()
// on 8-XCD MI355X costs ~50us per sync (cross-XCD L2 coherence); plain same-stream
// launch-to-launch latency (~2us) is the cheap sync primitive here.
__global__ void kprep(const float* __restrict__ w, float* __restrict__ pmin, float* __restrict__ pmax,
                      float* __restrict__ veff, float* __restrict__ vid) {
    int tid = blockIdx.x * blockDim.x + threadIdx.x;
    float lo = 1e30f, hi = -1e30f;
    const float4* w4 = (const float4*)w;
    const int n4 = (IN_F * OUT_F) / 4;                    // 262144
    for (int i = tid; i < n4; i += 256 * 256) {
        float4 q = w4[i];
        lo = fminf(lo, fminf(fminf(q.x, q.y), fminf(q.z, q.w)));
        hi = fmaxf(hi, fmaxf(fmaxf(q.x, q.y), fmaxf(q.z, q.w)));
    }
#pragma unroll
    for (int m = 1; m < 64; m <<= 1) {
        lo = fminf(lo, __shfl_xor(lo, m, 64));
        hi = fmaxf(hi, __shfl_xor(hi, m, 64));
    }
    __shared__ float slo[4], shi[4];
    int wv = threadIdx.x >> 6, ln = threadIdx.x & 63;
    if (ln == 0) { slo[wv] = lo; shi[wv] = hi; }
    __syncthreads();
    if (threadIdx.x == 0) {
        pmin[blockIdx.x] = fminf(fminf(slo[0], slo[1]), fminf(slo[2], slo[3]));
        pmax[blockIdx.x] = fmaxf(fmaxf(shi[0], shi[1]), fmaxf(shi[2], shi[3]));
    }
    if (blockIdx.x == 0) {                                 // zero accumulators for K2's atomics
        float4 z = make_float4(0.f, 0.f, 0.f, 0.f);
        ((float4*)veff)[threadIdx.x] = z;                  // 256 * 4 = 1024
        ((float4*)vid)[threadIdx.x]  = z;
    }
}

// ---------- K2: build W_effT bf16 + accumulate veff/vid (64 blocks x 16 rows) ----------
// R6 post-mortem: 64x16 is the TIMED-fast config. The 256x4 variant costs +12.6us real
// (524K vs 131K serialized global f32 atomics, G12). R5's rocprof "44us / 2.4% occ" for
// this kernel is a REPLAY ARTIFACT: isolated replay runs it cold, but in the timed chain
// w is L2/L3-hot from kprep one dispatch earlier. Do not "fix" this kernel from replay
// counters again.
__global__ void kbuildvec(const float* __restrict__ w, const float* __restrict__ pmin,
                          const float* __restrict__ pmax, unsigned short* __restrict__ bt,
                          float* __restrict__ veff, float* __restrict__ vid) {
    float lo = pmin[threadIdx.x], hi = pmax[threadIdx.x];
#pragma unroll
    for (int m = 1; m < 64; m <<= 1) {
        lo = fminf(lo, __shfl_xor(lo, m, 64));
        hi = fmaxf(hi, __shfl_xor(hi, m, 64));
    }
    __shared__ float slo[4], shi[4];
    int wv = threadIdx.x >> 6, ln = threadIdx.x & 63;
    if (ln == 0) { slo[wv] = lo; shi[wv] = hi; }
    __syncthreads();
    float wmin = fminf(fminf(slo[0], slo[1]), fminf(slo[2], slo[3]));
    float wmax = fmaxf(fmaxf(shi[0], shi[1]), fmaxf(shi[2], shi[3]));

    float inv_range = 1.0f / (wmax - wmin);
    float acoef = (G_LRS - G_HRS) * inv_range;
    float bcoef = G_HRS - acoef * wmin;
    float inva = 1.0f / acoef;

    int k0 = threadIdx.x * 4;
    float se[4] = {0.f, 0.f, 0.f, 0.f}, si[4] = {0.f, 0.f, 0.f, 0.f};
#pragma unroll
    for (int rr = 0; rr < 16; rr++) {
        int n = blockIdx.x * 16 + rr;
        float4 q = *(const float4*)&w[(size_t)n * IN_F + k0];
        float wvv[4] = { q.x, q.y, q.z, q.w };
        unsigned short o[4];
#pragma unroll
        for (int j = 0; j < 4; j++) {
            int k = k0 + j;
            float g = quant_g(wvv[j], wmin, inv_range);
            float r = PAR_R * ((float)(n + 1) + (float)(IN_F - k));
            float ge = 1.0f / (1.0f / g + r);
            o[j] = f2bf((ge - bcoef) * inva);
            se[j] += ge;
            si[j] += g;
        }
        uint2 ov;
        ov.x = (unsigned int)o[0] | ((unsigned int)o[1] << 16);
        ov.y = (unsigned int)o[2] | ((unsigned int)o[3] << 16);
        *(uint2*)&bt[(size_t)n * IN_F + k0] = ov;
    }
#pragma unroll
    for (int j = 0; j < 4; j++) {
        atomicAdd(&veff[k0 + j], se[j]);
        atomicAdd(&vid[k0 + j], si[j]);
    }
}

// ---------- K3: corr[row] = (x.v_eff)/(x.v_id); emit bf16 copy of x ----------
// barrier-free: one wave per row, 4 rows per block. Fully-coalesced pattern:
// iteration p, lane l touches floats [p*256 + l*4, +4) -> 1KB contiguous per wave inst.
__global__ void kcorr(const float* __restrict__ x, const float* __restrict__ veff,
                      const float* __restrict__ vid, float* __restrict__ corr,
                      unsigned short* __restrict__ abf) {
    int row = blockIdx.x * 4 + (threadIdx.x >> 6);
    int lane = threadIdx.x & 63;
    const float* xr = x + (size_t)row * IN_F;
    float se = 0.f, si = 0.f;
#pragma unroll
    for (int p = 0; p < 4; p++) {
        int off = p * 256 + lane * 4;
        float4 q  = *(const float4*)(xr + off);
        float4 ve = *(const float4*)(veff + off);
        float4 vi = *(const float4*)(vid  + off);
        se += q.x * ve.x + q.y * ve.y + q.z * ve.z + q.w * ve.w;
        si += q.x * vi.x + q.y * vi.y + q.z * vi.z + q.w * vi.w;
        if (abf) {
            uint2 ov;
            ov.x = (unsigned int)f2bf(q.x) | ((unsigned int)f2bf(q.y) << 16);
            ov.y = (unsigned int)f2bf(q.z) | ((unsigned int)f2bf(q.w) << 16);
            *(uint2*)&abf[(size_t)row * IN_F + off] = ov;
        }
    }
#pragma unroll
    for (int m = 1; m < 64; m <<= 1) {
        se += __shfl_xor(se, m, 64);
        si += __shfl_xor(si, m, 64);
    }
    if (lane == 0) corr[row] = se / si;
}

// ---------- K4 common ----------
typedef __attribute__((ext_vector_type(8))) short bf16x8;
typedef __attribute__((ext_vector_type(4))) float f32x4;

#define GLD_LDS16(g, l) \
    __builtin_amdgcn_global_load_lds((const __attribute__((address_space(1))) void*)(g), \
                                     (__attribute__((address_space(3))) void*)(l), 16, 0, 0)

#define SCHED0   __builtin_amdgcn_sched_barrier(0)
#define LGKM(n)  do { asm volatile("s_waitcnt lgkmcnt(" #n ")" ::: "memory"); SCHED0; } while (0)
#define VMCNT(n) asm volatile("s_waitcnt vmcnt(" #n ")" ::: "memory")
#define SBAR     asm volatile("s_barrier" ::: "memory")

#define MFMA_ROW4(MT, A, B0, B1, B2, B3) \
    acc[MT][0] = __builtin_amdgcn_mfma_f32_16x16x32_bf16(A, B0, acc[MT][0], 0, 0, 0); \
    acc[MT][1] = __builtin_amdgcn_mfma_f32_16x16x32_bf16(A, B1, acc[MT][1], 0, 0, 0); \
    acc[MT][2] = __builtin_amdgcn_mfma_f32_16x16x32_bf16(A, B2, acc[MT][2], 0, 0, 0); \
    acc[MT][3] = __builtin_amdgcn_mfma_f32_16x16x32_bf16(A, B3, acc[MT][3], 0, 0, 0);

// ---------- K4 (full path): pipelined GEMM, 128x128 tile, BK=64, 4 waves.
// Schedule (correctness-verified in R3/R5 runs): all 8 next-tile stages issue in ph0
// (B'x4) / ph1 (A'u0,u2 then u1,u3; order pinned). S1 = vmcnt(4) retires prev A'u1,u3
// (3 phases old); S2 = vmcnt(2) retires B'x4 + A'u0,u2, leaves A'u1,u3 in flight.
// WAR-safe: all ds_reads of a buffer complete before its overwrite barrier.
__global__ __launch_bounds__(256) void kgemm2(
    const unsigned short* __restrict__ Abf,  // x bf16 [8192,1024]
    const unsigned short* __restrict__ Bt,   // W_effT [1024,1024] bf16
    const float* __restrict__ bias,          // [1024] f32
    const float* __restrict__ corr,          // [8192] f32
    float* __restrict__ out)                 // [8192,1024] f32
{
    __shared__ unsigned short As[2 * 128 * 64];   // 2 x 16KB
    __shared__ unsigned short Bs[2 * 128 * 64];   // 2 x 16KB
    const int tid = threadIdx.x;
    const int f = blockIdx.x;
    const int bm = ((f & 7) * 8 + ((f >> 3) & 7)) * 128;
    const int bn = (f >> 6) * 128;
    const int wave = tid >> 6, lane = tid & 63;
    const int wmL = (wave >> 1) * 64;
    const int wnL = (wave & 1) * 64;
    const int fr = lane & 15;
    const int quad = lane >> 4;

    const int sw   = (fr & 7) * 16;
    const int aRd0 = (wmL + fr) * 128 + ((quad * 16) ^ sw);        // ks=0
    const int aRd1 = (wmL + fr) * 128 + (((64 + quad * 16)) ^ sw); // ks=1
    const int bRd0 = (wnL + fr) * 128 + ((quad * 16) ^ sw);
    const int bRd1 = (wnL + fr) * 128 + (((64 + quad * 16)) ^ sw);

    const int arow  = tid >> 3;                                  // 0..31
    const int acolb = ((tid & 7) * 16) ^ ((arow & 7) * 16);
    const unsigned short* gA = Abf + (size_t)(bm + arow) * IN_F + (acolb >> 1);
    const unsigned short* gB = Bt  + (size_t)(bn + arow) * IN_F + (acolb >> 1);

    f32x4 acc[4][4] = {};

    // ---- prologue: stage tile 0 into buf0, drain once, publish
    {
        unsigned short* lA = As + tid * 8;
        unsigned short* lB = Bs + tid * 8;
        GLD_LDS16(gB,              lB);
        GLD_LDS16(gB + 32 * IN_F,  lB + 2048);
        GLD_LDS16(gB + 64 * IN_F,  lB + 4096);
        GLD_LDS16(gB + 96 * IN_F,  lB + 6144);
        GLD_LDS16(gA,              lA);
        GLD_LDS16(gA + 32 * IN_F,  lA + 2048);
        GLD_LDS16(gA + 64 * IN_F,  lA + 4096);
        GLD_LDS16(gA + 96 * IN_F,  lA + 6144);
        VMCNT(0);
        SBAR;
    }

#pragma unroll 1
    for (int t = 0; t < 15; ++t) {
        const int rb = (t & 1) << 13;          // read buf ushort offset (0 / 8192)
        const int wb = rb ^ 8192;
        const int kbn = t * 64 + 64;
        const char* Ar = (const char*)(As + rb);
        const char* Br = (const char*)(Bs + rb);
        unsigned short* Aw = As + wb + tid * 8;
        unsigned short* Bw = Bs + wb + tid * 8;
        bf16x8 b0, b1, b2, b3, a0, a1;     // ks0 frags
        bf16x8 c0, c1, c2, c3, p0, p1;     // ks1 prefetch (B all, A mt0/mt1)
        bf16x8 q0, q1;                     // ks1 A mt2/mt3 prefetch

        // ---- phase 0: ks0 x mt{0,1}; prefetch ph2 reads; stage B'u0-u3
        b0 = *(const bf16x8*)(Br + bRd0);
        b1 = *(const bf16x8*)(Br + bRd0 + 2048);
        b2 = *(const bf16x8*)(Br + bRd0 + 4096);
        b3 = *(const bf16x8*)(Br + bRd0 + 6144);
        a0 = *(const bf16x8*)(Ar + aRd0);
        a1 = *(const bf16x8*)(Ar + aRd0 + 2048);
        SCHED0;                                    // pin group order for counted lgkm
        c0 = *(const bf16x8*)(Br + bRd1);
        c1 = *(const bf16x8*)(Br + bRd1 + 2048);
        c2 = *(const bf16x8*)(Br + bRd1 + 4096);
        c3 = *(const bf16x8*)(Br + bRd1 + 6144);
        p0 = *(const bf16x8*)(Ar + aRd1);
        p1 = *(const bf16x8*)(Ar + aRd1 + 2048);
        GLD_LDS16(gB + kbn,             Bw);
        GLD_LDS16(gB + 32 * IN_F + kbn, Bw + 2048);
        GLD_LDS16(gB + 64 * IN_F + kbn, Bw + 4096);
        GLD_LDS16(gB + 96 * IN_F + kbn, Bw + 6144);
        LGKM(6);                                   // own 6 done; prefetch 6 may pend
        __builtin_amdgcn_s_setprio(1);
        MFMA_ROW4(0, a0, b0, b1, b2, b3)
        MFMA_ROW4(1, a1, b0, b1, b2, b3)
        __builtin_amdgcn_s_setprio(0);
        SCHED0;
        VMCNT(4);                                  // retires prev tile's A'u1,u3
        SBAR;

        // ---- phase 1: ks0 x mt{2,3}; prefetch ph3's A; stage A'u0,u2 then u1,u3
        a0 = *(const bf16x8*)(Ar + aRd0 + 4096);
        a1 = *(const bf16x8*)(Ar + aRd0 + 6144);
        SCHED0;
        q0 = *(const bf16x8*)(Ar + aRd1 + 4096);
        q1 = *(const bf16x8*)(Ar + aRd1 + 6144);
        GLD_LDS16(gA + kbn,             Aw);
        GLD_LDS16(gA + 64 * IN_F + kbn, Aw + 4096);
        SCHED0;                                    // pin A' issue order: u0,u2 before u1,u3
        GLD_LDS16(gA + 32 * IN_F + kbn, Aw + 2048);
        GLD_LDS16(gA + 96 * IN_F + kbn, Aw + 6144);
        LGKM(2);                                   // own 2 + ph0 prefetch done; q0/q1 pend
        __builtin_amdgcn_s_setprio(1);
        MFMA_ROW4(2, a0, b0, b1, b2, b3)
        MFMA_ROW4(3, a1, b0, b1, b2, b3)
        __builtin_amdgcn_s_setprio(0);
        SCHED0;

        // ---- phase 2: ks1 x mt{0,1} — data already in c*/p* registers
        LGKM(2);                                   // no-op belt+suspenders
        __builtin_amdgcn_s_setprio(1);
        MFMA_ROW4(0, p0, c0, c1, c2, c3)
        MFMA_ROW4(1, p1, c0, c1, c2, c3)
        __builtin_amdgcn_s_setprio(0);
        SCHED0;

        // ---- phase 3: ks1 x mt{2,3} — q0/q1 landed under ph2's MFMAs
        LGKM(0);
        __builtin_amdgcn_s_setprio(1);
        MFMA_ROW4(2, q0, c0, c1, c2, c3)
        MFMA_ROW4(3, q1, c0, c1, c2, c3)
        __builtin_amdgcn_s_setprio(0);
        SCHED0;
        VMCNT(2);                                  // retires B'x4 + A'u0,u2
        SBAR;
    }

    // ---- peeled tile 15 (buf1): no stages; first vmcnt drains last 2 in-flight loads.
    {
        const char* Ar = (const char*)(As + 8192);
        const char* Br = (const char*)(Bs + 8192);
        bf16x8 b0, b1, b2, b3, a0, a1;

        b0 = *(const bf16x8*)(Br + bRd0);
        b1 = *(const bf16x8*)(Br + bRd0 + 2048);
        b2 = *(const bf16x8*)(Br + bRd0 + 4096);
        b3 = *(const bf16x8*)(Br + bRd0 + 6144);
        a0 = *(const bf16x8*)(Ar + aRd0);
        a1 = *(const bf16x8*)(Ar + aRd0 + 2048);
        LGKM(0);
        __builtin_amdgcn_s_setprio(1);
        MFMA_ROW4(0, a0, b0, b1, b2, b3)
        MFMA_ROW4(1, a1, b0, b1, b2, b3)
        __builtin_amdgcn_s_setprio(0);
        SCHED0;
        VMCNT(0);
        SBAR;

        a0 = *(const bf16x8*)(Ar + aRd0 + 4096);
        a1 = *(const bf16x8*)(Ar + aRd0 + 6144);
        LGKM(0);
        __builtin_amdgcn_s_setprio(1);
        MFMA_ROW4(2, a0, b0, b1, b2, b3)
        MFMA_ROW4(3, a1, b0, b1, b2, b3)
        __builtin_amdgcn_s_setprio(0);
        SCHED0;

        b0 = *(const bf16x8*)(Br + bRd1);
        b1 = *(const bf16x8*)(Br + bRd1 + 2048);
        b2 = *(const bf16x8*)(Br + bRd1 + 4096);
        b3 = *(const bf16x8*)(Br + bRd1 + 6144);
        a0 = *(const bf16x8*)(Ar + aRd1);
        a1 = *(const bf16x8*)(Ar + aRd1 + 2048);
        LGKM(0);
        __builtin_amdgcn_s_setprio(1);
        MFMA_ROW4(0, a0, b0, b1, b2, b3)
        MFMA_ROW4(1, a1, b0, b1, b2, b3)
        __builtin_amdgcn_s_setprio(0);
        SCHED0;

        a0 = *(const bf16x8*)(Ar + aRd1 + 4096);
        a1 = *(const bf16x8*)(Ar + aRd1 + 6144);
        LGKM(0);
        __builtin_amdgcn_s_setprio(1);
        MFMA_ROW4(2, a0, b0, b1, b2, b3)
        MFMA_ROW4(3, a1, b0, b1, b2, b3)
        __builtin_amdgcn_s_setprio(0);
        SCHED0;
    }

    // epilogue: out[r][c] = acc + bias[c]*corr[r]  (C/D: col=lane&15, row=quad*4+reg)
#pragma unroll
    for (int nt = 0; nt < 4; nt++) {
        int gc = bn + wnL + nt * 16 + fr;
        float bv = bias[gc];
#pragma unroll
        for (int mt = 0; mt < 4; mt++) {
#pragma unroll
            for (int r = 0; r < 4; r++) {
                int gr = bm + wmL + mt * 16 + quad * 4 + r;
                out[(size_t)gr * OUT_F + gc] = acc[mt][nt][r] + bv * corr[gr];
            }
        }
    }
}

// ---------- K4 fallback (small workspace): converts x f32 -> bf16 in-kernel ----------
__global__ __launch_bounds__(256) void kgemm_conva(
    const float* __restrict__ Af32,
    const unsigned short* __restrict__ Bt,   // W_effT [1024,1024] bf16
    const float* __restrict__ bias,          // [1024] f32
    const float* __restrict__ corr,          // [8192] f32
    float* __restrict__ out)                 // [8192,1024] f32
{
    __shared__ unsigned short As0[128 * 32];
    __shared__ unsigned short As1[128 * 32];
    __shared__ unsigned short Bs0[128 * 32];
    __shared__ unsigned short Bs1[128 * 32];
    const int tid = threadIdx.x;
    const int f = blockIdx.x;
    const int bm = ((f & 7) * 8 + ((f >> 3) & 7)) * 128;
    const int bn = (f >> 6) * 128;
    const int wave = tid >> 6, lane = tid & 63;
    const int wmL = (wave >> 1) * 64;
    const int wnL = (wave & 1) * 64;
    const int fr = lane & 15;
    const int fk = (lane >> 4) * 8;
    const int quad = lane >> 4;

    f32x4 acc[4][4] = {};

    const int c0 = tid, c1 = tid + 256;
    const unsigned short* gB0 = Bt + (size_t)(bn + (c0 >> 2)) * IN_F + ((c0 & 3) << 3);
    const unsigned short* gB1 = Bt + (size_t)(bn + (c1 >> 2)) * IN_F + ((c1 & 3) << 3);
    const float* fA0 = Af32 + (size_t)(bm + (c0 >> 2)) * IN_F + ((c0 & 3) << 3);
    const float* fA1 = Af32 + (size_t)(bm + (c1 >> 2)) * IN_F + ((c1 & 3) << 3);

    for (int kb = 0; kb < IN_F; kb += 64) {
        float4 p[8];
        p[0] = *(const float4*)(fA0 + kb);      p[1] = *(const float4*)(fA0 + kb + 4);
        p[2] = *(const float4*)(fA1 + kb);      p[3] = *(const float4*)(fA1 + kb + 4);
        p[4] = *(const float4*)(fA0 + kb + 32); p[5] = *(const float4*)(fA0 + kb + 36);
        p[6] = *(const float4*)(fA1 + kb + 32); p[7] = *(const float4*)(fA1 + kb + 36);
        uint4 u[4];
#pragma unroll
        for (int j = 0; j < 4; j++) {
            u[j] = make_uint4(
                (unsigned int)f2bf(p[2*j].x) | ((unsigned int)f2bf(p[2*j].y) << 16),
                (unsigned int)f2bf(p[2*j].z) | ((unsigned int)f2bf(p[2*j].w) << 16),
                (unsigned int)f2bf(p[2*j+1].x) | ((unsigned int)f2bf(p[2*j+1].y) << 16),
                (unsigned int)f2bf(p[2*j+1].z) | ((unsigned int)f2bf(p[2*j+1].w) << 16));
        }
        __syncthreads();
        *(uint4*)&As0[c0 * 8] = u[0];
        *(uint4*)&As0[c1 * 8] = u[1];
        *(uint4*)&As1[c0 * 8] = u[2];
        *(uint4*)&As1[c1 * 8] = u[3];
        GLD_LDS16(gB0 + kb, &Bs0[c0 * 8]);
        GLD_LDS16(gB1 + kb, &Bs0[c1 * 8]);
        GLD_LDS16(gB0 + kb + 32, &Bs1[c0 * 8]);
        GLD_LDS16(gB1 + kb + 32, &Bs1[c1 * 8]);
        __syncthreads();

        bf16x8 af[4], bfv[4];
#pragma unroll
        for (int mt = 0; mt < 4; mt++)
            af[mt] = *(const bf16x8*)&As0[(wmL + mt * 16 + fr) * 32 + fk];
#pragma unroll
        for (int nt = 0; nt < 4; nt++)
            bfv[nt] = *(const bf16x8*)&Bs0[(wnL + nt * 16 + fr) * 32 + fk];
#pragma unroll
        for (int mt = 0; mt < 4; mt++)
#pragma unroll
            for (int nt = 0; nt < 4; nt++)
                acc[mt][nt] = __builtin_amdgcn_mfma_f32_16x16x32_bf16(af[mt], bfv[nt], acc[mt][nt], 0, 0, 0);
#pragma unroll
        for (int mt = 0; mt < 4; mt++)
            af[mt] = *(const bf16x8*)&As1[(wmL + mt * 16 + fr) * 32 + fk];
#pragma unroll
        for (int nt = 0; nt < 4; nt++)
            bfv[nt] = *(const bf16x8*)&Bs1[(wnL + nt * 16 + fr) * 32 + fk];
#pragma unroll
        for (int mt = 0; mt < 4; mt++)
#pragma unroll
            for (int nt = 0; nt < 4; nt++)
                acc[mt][nt] = __builtin_amdgcn_mfma_f32_16x16x32_bf16(af[mt], bfv[nt], acc[mt][nt], 0, 0, 0);
    }

#pragma unroll
    for (int nt = 0; nt < 4; nt++) {
        int gc = bn + wnL + nt * 16 + fr;
        float bv = bias[gc];
#pragma unroll
        for (int mt = 0; mt < 4; mt++) {
#pragma unroll
            for (int r = 0; r < 4; r++) {
                int gr = bm + wmL + mt * 16 + quad * 4 + r;
                out[(size_t)gr * OUT_F + gc] = acc[mt][nt][r] + bv * corr[gr];
            }
        }
    }
}

// ---------- launch ----------
extern "C" void kernel_launch(void* const* d_in, const int* in_sizes, int n_in,
                              void* d_out, int out_size, void* d_ws, size_t ws_size,
                              hipStream_t stream) {
    const float* x    = (const float*)d_in[0];   // [8192,1024] f32
    const float* w    = (const float*)d_in[1];   // [1024,1024] f32 (out,in)
    const float* bias = (const float*)d_in[2];   // [1024] f32
    float* out = (float*)d_out;

    char* ws = (char*)d_ws;
    float* pmin        = (float*)(ws + WS_PMIN);
    float* pmax        = (float*)(ws + WS_PMAX);
    float* veff        = (float*)(ws + WS_VEFF);
    float* vid         = (float*)(ws + WS_VID);
    float* corr        = (float*)(ws + WS_CORR);
    unsigned short* bt = (unsigned short*)(ws + WS_BT);
    unsigned short* abf = (unsigned short*)(ws + WS_ABF);

    bool full = ws_size >= WS_NEED_FULL;

    kprep<<<256, 256, 0, stream>>>(w, pmin, pmax, veff, vid);
    kbuildvec<<<OUT_F / 16, 256, 0, stream>>>(w, pmin, pmax, bt, veff, vid);
    kcorr<<<BATCH / 4, 256, 0, stream>>>(x, veff, vid, corr, full ? abf : nullptr);
    if (full)
        kgemm2<<<512, 256, 0, stream>>>(abf, bt, bias, corr, out);
    else
        kgemm_conva<<<512, 256, 0, stream>>>(x, bt, bias, corr, out);
}